// Round 7
// baseline (156.500 us; speedup 1.0000x reference)
//
#include <hip/hip_runtime.h>
#include <hip/hip_bf16.h>

#define B_  2
#define S_  512
#define H_  8
#define D_  32
#define DM_ 256
#define HD_ 256
#define NROW 8         // rows per qkv block
#define TI  4          // i-rows per attention block
#define CH  64         // rpe chunk rows staged per buffer

// ---------------------------------------------------------------------------
// Kernel A: QKV projection.  grid = (B*S/NROW, 3), block = 256.
// out layout: (b, h, s, d).  q is pre-scaled by 1/sqrt(D).
// ---------------------------------------------------------------------------
__global__ __launch_bounds__(256) void qkv_kernel(
    const float* __restrict__ hid, const float* __restrict__ wq,
    const float* __restrict__ wk, const float* __restrict__ wv,
    float* __restrict__ qo, float* __restrict__ ko, float* __restrict__ vo)
{
  __shared__ __align__(16) float hs[NROW][DM_];
  const int r0 = blockIdx.x * NROW;                 // global row in [0, B*S)
  const float* w   = (blockIdx.y == 0) ? wq : (blockIdx.y == 1) ? wk : wv;
  float*       out = (blockIdx.y == 0) ? qo : (blockIdx.y == 1) ? ko : vo;
  const float mulf = (blockIdx.y == 0) ? 0.17677669529663687f : 1.0f;
  const int tid = threadIdx.x;

  for (int idx = tid; idx < NROW * DM_; idx += 256)
    hs[idx >> 8][idx & 255] = hid[r0 * DM_ + idx];
  __syncthreads();

  float acc[NROW] = {0.f, 0.f, 0.f, 0.f, 0.f, 0.f, 0.f, 0.f};
  const float* wp = w + tid;                        // column m = tid
  #pragma unroll 4
  for (int c4 = 0; c4 < DM_ / 4; ++c4) {
    const float w0 = wp[(4 * c4 + 0) * HD_];
    const float w1 = wp[(4 * c4 + 1) * HD_];
    const float w2 = wp[(4 * c4 + 2) * HD_];
    const float w3 = wp[(4 * c4 + 3) * HD_];
    #pragma unroll
    for (int r = 0; r < NROW; ++r) {
      const float4 hv = reinterpret_cast<const float4*>(&hs[r][0])[c4];
      acc[r] = fmaf(hv.x, w0, acc[r]);
      acc[r] = fmaf(hv.y, w1, acc[r]);
      acc[r] = fmaf(hv.z, w2, acc[r]);
      acc[r] = fmaf(hv.w, w3, acc[r]);
    }
  }
  const int h = tid >> 5, d = tid & 31;
  #pragma unroll
  for (int r = 0; r < NROW; ++r) {
    const int g = r0 + r;
    const int b = g >> 9, s = g & (S_ - 1);
    out[((b * H_ + h) * S_ + s) * D_ + d] = acc[r] * mulf;
  }
}

// 4-lane (quad) butterfly sum via DPP: all 4 lanes of the quad get the sum.
__device__ __forceinline__ float red4(float x) {
  int i;
  i = __builtin_amdgcn_mov_dpp(__float_as_int(x), 0xB1, 0xf, 0xf, true); // quad_perm xor1
  x += __int_as_float(i);
  i = __builtin_amdgcn_mov_dpp(__float_as_int(x), 0x4E, 0xf, 0xf, true); // quad_perm xor2
  x += __int_as_float(i);
  return x;
}

// swizzled float4 slot within a CH*D_ rpe chunk (jj = local row, c = 16B col)
#define RSL(jj, c) (((jj) << 3) | ((c) ^ ((jj) & 7)))

// ---------------------------------------------------------------------------
// Kernel B (fused): scores + mask + softmax + attn@V + fc + residual + LN.
// R6 post-mortem: byte model held (attn < 41 us); q/V/fcw still scale as
// 1/TI.  R7: TI=4, grid = 256 = exactly 1 block/CU.  Traffic 550 -> ~355 MB
// (q 128, V 128, fcw 64, rpe 32 floor).  LDS ~136 KB -> 1 block/CU,
// 8 waves/CU: occupancy deliberately traded for ILP (the anti-R4 bet):
// __launch_bounds__(512,2) gives a 256-VGPR budget (live ~130 -> no squeeze,
// no spill), PV unroll x4, rpe chunk prefetch issued BEFORE current-chunk
// compute.  Wave w owns head w; q/V loads amortized over 4 i-rows.
// Score mapping: lane=(j4,dq).  attn@V mapping: lane=(j8,dc).
// scores[ii,h,j] = sum_d q'[h,j,d] k[h,i0+ii,d] rpe[i0+ii,j,d];
// mask: j < station OR j == i.
// ---------------------------------------------------------------------------
__global__ __launch_bounds__(512, 2) void attn_fused_kernel(
    const float* __restrict__ rpe, const float* __restrict__ q_ws,
    const float* __restrict__ k_ws, const float* __restrict__ v_ws,
    const int* __restrict__ station_p, const float* __restrict__ fc_w,
    const float* __restrict__ fc_b, const float* __restrict__ hid,
    const float* __restrict__ ln_w, const float* __restrict__ ln_b,
    float* __restrict__ out)
{
  __shared__ __align__(16) float p_smem[TI][H_][S_];      // 64 KB
  __shared__ __align__(16) float rpe_s[2][TI][CH * D_];   // 64 KB, swizzled
  __shared__ __align__(16) float ks[TI][H_ * D_];         // 4 KB
  __shared__ __align__(16) float orow[TI][HD_];           // 4 KB
  __shared__ float sums[TI][H_];
  __shared__ float redm[TI][4];
  __shared__ float redvr[TI][4];

  const int tid  = threadIdx.x;
  const int w    = tid >> 6, lane = tid & 63;
  const int j4   = lane >> 2, dq = lane & 3;        // score mapping
  const int j8   = lane >> 3, dc = lane & 7;        // attn@V mapping
  const int n    = blockIdx.x;                      // 0..255
  const int b    = n >> 7;
  const int i0   = (n & 127) * TI;
  const int HS   = S_ * D_;                         // head stride

  int station = station_p[0];
  station = station > S_ ? S_ : (station < 0 ? 0 : station);

  const float* qb = q_ws + (size_t)(b * H_) * S_ * D_;
  const float* kb = k_ws + (size_t)(b * H_) * S_ * D_;
  const float* vb = v_ws + (size_t)(b * H_) * S_ * D_;
  const float* rbp[TI];
  #pragma unroll
  for (int ii = 0; ii < TI; ++ii)
    rbp[ii] = rpe + ((size_t)(b * S_ + i0 + ii) * S_) * D_;

  // stage K rows i0..i0+3 (all 8 heads): 4096 elements, 8/thread
  for (int idx = tid; idx < TI * H_ * D_; idx += 512) {
    const int ii = idx >> 8, rest = idx & 255;
    ks[ii][rest] = kb[(rest >> 5) * HS + (i0 + ii) * D_ + (rest & 31)];
  }
  // stage rpe chunk 0 (swizzled); 512 float4 per i-row = 1/thread each
  const int nc = (station + CH - 1) >> 6;           // chunks of 64 j
  {
    const int jj = tid >> 3, cs = tid & 7;
    const int sl = RSL(jj, cs);
    if (nc > 0) {
      #pragma unroll
      for (int ii = 0; ii < TI; ++ii)
        reinterpret_cast<float4*>(&rpe_s[0][ii][0])[sl] =
            reinterpret_cast<const float4*>(rbp[ii])[tid];
    }
  }
  __syncthreads();

  // hoisted K fragments for this wave's head (32 VGPRs)
  float4 kA[TI], kB[TI];
  #pragma unroll
  for (int ii = 0; ii < TI; ++ii) {
    kA[ii] = *reinterpret_cast<const float4*>(&ks[ii][w * D_ + dq * 8]);
    kB[ii] = *reinterpret_cast<const float4*>(&ks[ii][w * D_ + dq * 8 + 4]);
  }
  const float* qh = qb + w * HS;

  // ---- scores: chunked over j; prefetch next chunk before compute ----
  for (int c = 0; c < nc; ++c) {
    if (c) __syncthreads();                         // chunk c staged; c-1 reads done
    if (c + 1 < nc) {                               // stage next chunk (issue early)
      const int jj = tid >> 3, cs = tid & 7;
      const int sl = RSL(jj, cs);
      const int buf = (c + 1) & 1;
      #pragma unroll
      for (int ii = 0; ii < TI; ++ii)
        reinterpret_cast<float4*>(&rpe_s[buf][ii][0])[sl] =
            reinterpret_cast<const float4*>(rbp[ii] + (c + 1) * CH * D_)[tid];
    }
    const int cb = c & 1;
    #pragma unroll 2
    for (int p = 0; p < CH / 16; ++p) {
      const int jl = p * 16 + j4;                   // local j in chunk
      const int j  = c * CH + jl;                   // j <= 511 always
      const float4 q0 = *reinterpret_cast<const float4*>(qh + j * D_ + dq * 8);
      const float4 q1 = *reinterpret_cast<const float4*>(qh + j * D_ + dq * 8 + 4);
      #pragma unroll
      for (int ii = 0; ii < TI; ++ii) {
        const float4* rs = reinterpret_cast<const float4*>(&rpe_s[cb][ii][0]);
        const float4 r0 = rs[RSL(jl, 2 * dq)];
        const float4 r1 = rs[RSL(jl, 2 * dq + 1)];
        float s = q0.x * kA[ii].x * r0.x;
        s = fmaf(q0.y * kA[ii].y, r0.y, s);
        s = fmaf(q0.z * kA[ii].z, r0.z, s);
        s = fmaf(q0.w * kA[ii].w, r0.w, s);
        s = fmaf(q1.x * kB[ii].x, r1.x, s);
        s = fmaf(q1.y * kB[ii].y, r1.y, s);
        s = fmaf(q1.z * kB[ii].z, r1.z, s);
        s = fmaf(q1.w * kB[ii].w, r1.w, s);
        s = red4(s);
        if (dq == 0 && j < station) p_smem[ii][w][j] = s;
      }
    }
  }
  // diagonal cells j == i0+ii when beyond station (lanes 0..3; rpe/q global)
  if (j4 == 0) {
    #pragma unroll
    for (int ii = 0; ii < TI; ++ii) {
      const int ig = i0 + ii;
      if (ig >= station) {
        const float4 r0 = *reinterpret_cast<const float4*>(rbp[ii] + ig * D_ + dq * 8);
        const float4 r1 = *reinterpret_cast<const float4*>(rbp[ii] + ig * D_ + dq * 8 + 4);
        const float4 q0 = *reinterpret_cast<const float4*>(qh + ig * D_ + dq * 8);
        const float4 q1 = *reinterpret_cast<const float4*>(qh + ig * D_ + dq * 8 + 4);
        float s = q0.x * kA[ii].x * r0.x;
        s = fmaf(q0.y * kA[ii].y, r0.y, s);
        s = fmaf(q0.z * kA[ii].z, r0.z, s);
        s = fmaf(q0.w * kA[ii].w, r0.w, s);
        s = fmaf(q1.x * kB[ii].x, r1.x, s);
        s = fmaf(q1.y * kB[ii].y, r1.y, s);
        s = fmaf(q1.z * kB[ii].z, r1.z, s);
        s = fmaf(q1.w * kB[ii].w, r1.w, s);
        s = red4(s);
        if (dq == 0) p_smem[ii][w][ig] = s;
      }
    }
  }
  __syncthreads();

  // ---- softmax: wave w handles head w, TI rows sequentially ----
  #pragma unroll
  for (int ii = 0; ii < TI; ++ii) {
    float* pr = &p_smem[ii][w][0];
    const int ig = i0 + ii;
    const bool dxi = (ig >= station);
    float m = -1e30f;
    for (int jj = lane; jj < station; jj += 64) m = fmaxf(m, pr[jj]);
    const float dv = dxi ? pr[ig] : -1e30f;
    m = fmaxf(m, dv);
    #pragma unroll
    for (int o = 32; o; o >>= 1) m = fmaxf(m, __shfl_xor(m, o, 64));
    float sum = 0.f;
    for (int jj = lane; jj < station; jj += 64) {
      const float e = __expf(pr[jj] - m);
      pr[jj] = e;
      sum += e;
    }
    #pragma unroll
    for (int o = 32; o; o >>= 1) sum += __shfl_xor(sum, o, 64);
    if (dxi) {
      const float e = __expf(dv - m);
      sum += e;
      if (lane == 0) pr[ig] = e;
    }
    if (lane == 0) sums[ii][w] = sum;
  }
  __syncthreads();

  // ---- attn @ V: wave w owns head w; each V load feeds all TI i-rows ----
  float4 a[TI];
  #pragma unroll
  for (int ii = 0; ii < TI; ++ii) a[ii] = make_float4(0.f, 0.f, 0.f, 0.f);
  {
    const float* vh = vb + w * HS;
    #pragma unroll 4
    for (int jb = 0; jb < station; jb += 8) {
      const int j  = jb + j8;
      const int jc = j < S_ ? j : S_ - 1;
      const float4 v4 = *reinterpret_cast<const float4*>(vh + jc * D_ + dc * 4);
      #pragma unroll
      for (int ii = 0; ii < TI; ++ii) {
        float pv = 0.f;
        if (j < station) pv = p_smem[ii][w][j];
        a[ii].x = fmaf(pv, v4.x, a[ii].x);
        a[ii].y = fmaf(pv, v4.y, a[ii].y);
        a[ii].z = fmaf(pv, v4.z, a[ii].z);
        a[ii].w = fmaf(pv, v4.w, a[ii].w);
      }
    }
  }
  // reduce over j8 groups (lane bits 3..5)
  #pragma unroll
  for (int o = 8; o <= 32; o <<= 1) {
    #pragma unroll
    for (int ii = 0; ii < TI; ++ii) {
      a[ii].x += __shfl_xor(a[ii].x, o, 64);
      a[ii].y += __shfl_xor(a[ii].y, o, 64);
      a[ii].z += __shfl_xor(a[ii].z, o, 64);
      a[ii].w += __shfl_xor(a[ii].w, o, 64);
    }
  }
  if (j8 == 0) {
    #pragma unroll
    for (int ii = 0; ii < TI; ++ii) {
      const int ig = i0 + ii;
      if (ig >= station) {                          // diagonal, exactly once
        const float pv = p_smem[ii][w][ig];
        const float4 v4 = *reinterpret_cast<const float4*>(vb + w * HS + ig * D_ + dc * 4);
        a[ii].x = fmaf(pv, v4.x, a[ii].x);
        a[ii].y = fmaf(pv, v4.y, a[ii].y);
        a[ii].z = fmaf(pv, v4.z, a[ii].z);
        a[ii].w = fmaf(pv, v4.w, a[ii].w);
      }
      const float inv = 1.f / sums[ii][w];
      a[ii].x *= inv; a[ii].y *= inv; a[ii].z *= inv; a[ii].w *= inv;
      reinterpret_cast<float4*>(&orow[ii][w * D_])[dc] = a[ii];
    }
  }
  __syncthreads();

  // ---- fc (thread per output column m=tid, first 4 waves) + residual + LN --
  float f[TI] = {0.f, 0.f, 0.f, 0.f};
  if (tid < DM_) {
    const float* wp = fc_w + tid;
    #pragma unroll 4
    for (int n4 = 0; n4 < HD_ / 4; ++n4) {
      const float w0 = wp[(4 * n4 + 0) * DM_];
      const float w1 = wp[(4 * n4 + 1) * DM_];
      const float w2 = wp[(4 * n4 + 2) * DM_];
      const float w3 = wp[(4 * n4 + 3) * DM_];
      #pragma unroll
      for (int ii = 0; ii < TI; ++ii) {
        const float4 ov = reinterpret_cast<const float4*>(&orow[ii][0])[n4];
        f[ii] = fmaf(ov.x, w0, f[ii]);
        f[ii] = fmaf(ov.y, w1, f[ii]);
        f[ii] = fmaf(ov.z, w2, f[ii]);
        f[ii] = fmaf(ov.w, w3, f[ii]);
      }
    }
    const float bias = fc_b[tid];
    #pragma unroll
    for (int ii = 0; ii < TI; ++ii)
      f[ii] += bias + hid[(size_t)(b * S_ + i0 + ii) * DM_ + tid];
    #pragma unroll
    for (int ii = 0; ii < TI; ++ii) {
      float s = f[ii];
      #pragma unroll
      for (int o = 32; o; o >>= 1) s += __shfl_xor(s, o, 64);
      if (lane == 0) redm[ii][w] = s;
    }
  }
  __syncthreads();
  float dd[TI];
  #pragma unroll
  for (int ii = 0; ii < TI; ++ii) {
    const float mu = (redm[ii][0] + redm[ii][1] + redm[ii][2] + redm[ii][3]) * (1.f / DM_);
    dd[ii] = f[ii] - mu;
  }
  if (tid < DM_) {
    #pragma unroll
    for (int ii = 0; ii < TI; ++ii) {
      float s = dd[ii] * dd[ii];
      #pragma unroll
      for (int o = 32; o; o >>= 1) s += __shfl_xor(s, o, 64);
      if (lane == 0) redvr[ii][w] = s;
    }
  }
  __syncthreads();
  if (tid < DM_) {
    const float lw = ln_w[tid], lb = ln_b[tid];
    #pragma unroll
    for (int ii = 0; ii < TI; ++ii) {
      const float var = (redvr[ii][0] + redvr[ii][1] + redvr[ii][2] + redvr[ii][3]) * (1.f / DM_);
      out[(size_t)(b * S_ + i0 + ii) * DM_ + tid] =
          dd[ii] * rsqrtf(var + 1e-6f) * lw + lb;
    }
  }
}

// ---------------------------------------------------------------------------
extern "C" void kernel_launch(void* const* d_in, const int* in_sizes, int n_in,
                              void* d_out, int out_size, void* d_ws, size_t ws_size,
                              hipStream_t stream) {
  const float* hid = (const float*)d_in[0];
  const float* rpe = (const float*)d_in[1];
  const float* wq  = (const float*)d_in[2];
  const float* wk  = (const float*)d_in[3];
  const float* wv  = (const float*)d_in[4];
  const float* fcw = (const float*)d_in[5];
  const float* fcb = (const float*)d_in[6];
  const float* lnw = (const float*)d_in[7];
  const float* lnb = (const float*)d_in[8];
  const int* station = (const int*)d_in[9];
  float* out = (float*)d_out;

  const size_t per = (size_t)B_ * H_ * S_ * D_;   // 262144 floats
  float* q_ws = (float*)d_ws;
  float* k_ws = q_ws + per;
  float* v_ws = k_ws + per;

  dim3 gA(B_ * S_ / NROW, 3);
  qkv_kernel<<<gA, 256, 0, stream>>>(hid, wq, wk, wv, q_ws, k_ws, v_ws);
  attn_fused_kernel<<<B_ * S_ / TI, 512, 0, stream>>>(
      rpe, q_ws, k_ws, v_ws, station, fcw, fcb, hid, lnw, lnb, out);
}